// Round 6
// baseline (1945.817 us; speedup 1.0000x reference)
//
#include <hip/hip_runtime.h>
#include <hip/hip_bf16.h>
#include <stdint.h>

#define BB 8
#define NN 256
#define HH 512
#define G4 2048       // 4*HH
#define EE 512
#define RDIM 64
#define KX 576        // RDIM + EE
#define VV 32000
#define SLICES 64     // 64 hidden-slices of 8 units (x4 gates = 32 cols)

using f32x4 = __attribute__((ext_vector_type(4))) float;
using bf16x8 = __attribute__((ext_vector_type(8))) short;

__device__ __forceinline__ unsigned short f2bf(float f) {
  unsigned int u = __float_as_uint(f);
  u = (u + 0x7FFFu + ((u >> 16) & 1u)) >> 16;
  return (unsigned short)u;
}
__device__ __forceinline__ float bf2f(unsigned short s) {
  return __uint_as_float(((unsigned int)s) << 16);
}
__device__ __forceinline__ float sigm(float x) { return 1.0f / (1.0f + __expf(-x)); }

// ---------------- init: Hs[0]=root_h, Cs[0]=root_h (ref: Cs0 = Hs0)
__global__ void init_kernel(const float* __restrict__ root_h, float* __restrict__ Hs,
                            float* __restrict__ Cs) {
  int i = blockIdx.x * 256 + threadIdx.x;   // 0..4095
  float v = root_h[i];
  Hs[i] = v;
  Cs[i] = v;
}

// ---------------- Xg = concat(rel_emb[rel], word_emb[pword]) @ Wx + b
// grid (8 colblocks, 256 nodes), 256 threads. Xg layout [n][b][2048]
__global__ __launch_bounds__(256) void xg_kernel(
    const int* __restrict__ rel_ids, const int* __restrict__ sent_ids,
    const int* __restrict__ parent, const float* __restrict__ word_emb,
    const float* __restrict__ rel_emb, const float* __restrict__ Wx,
    const float* __restrict__ bias, float* __restrict__ Xg) {
  int n = blockIdx.y;
  int cb = blockIdx.x;
  int tid = threadIdx.x;
  __shared__ float xs[BB * KX];     // [b][k], k contiguous
  int par = parent[n];
  int b = tid >> 5;
  int l32 = tid & 31;
  int rid = rel_ids[b * NN + n];
  int pw = (par < 0) ? 0 : sent_ids[b * NN + par];   // SOS = 0
  const float* re = rel_emb + (size_t)rid * RDIM;
  const float* we = word_emb + (size_t)pw * EE;
  for (int q = l32; q < RDIM; q += 32) xs[b * KX + q] = re[q];
  for (int q = l32; q < EE; q += 32) xs[b * KX + RDIM + q] = we[q];
  __syncthreads();
  int col = cb * 256 + tid;
  float bb = bias[col];
  float acc[BB];
#pragma unroll
  for (int i = 0; i < BB; ++i) acc[i] = bb;
  const float* wxp = Wx + col;
  for (int k = 0; k < KX; k += 4) {
    float w0 = wxp[(size_t)(k + 0) * G4];
    float w1 = wxp[(size_t)(k + 1) * G4];
    float w2 = wxp[(size_t)(k + 2) * G4];
    float w3 = wxp[(size_t)(k + 3) * G4];
#pragma unroll
    for (int i = 0; i < BB; ++i) {
      f32x4 p = *(const f32x4*)&xs[i * KX + k];  // uniform broadcast
      acc[i] = fmaf(p[0], w0, acc[i]);
      acc[i] = fmaf(p[1], w1, acc[i]);
      acc[i] = fmaf(p[2], w2, acc[i]);
      acc[i] = fmaf(p[3], w3, acc[i]);
    }
  }
  float* xgout = Xg + (size_t)n * (BB * G4) + col;
#pragma unroll
  for (int i = 0; i < BB; ++i) xgout[(size_t)i * G4] = acc[i];
}

// ---------------- Wo (512 x 32000) f32  ->  WoT (32000 x 512) bf16
__global__ __launch_bounds__(256) void wot_kernel(const float* __restrict__ Wo,
                                                  unsigned short* __restrict__ WoT) {
  __shared__ float t[64][65];
  int n0 = blockIdx.x * 64;
  int k0 = blockIdx.y * 64;
  int tid = threadIdx.x;
  int c = tid & 63;
  int r4 = tid >> 6;
#pragma unroll
  for (int i = 0; i < 16; ++i) {
    int r = r4 * 16 + i;                       // local k
    t[r][c] = Wo[(size_t)(k0 + r) * VV + n0 + c];
  }
  __syncthreads();
#pragma unroll
  for (int i = 0; i < 16; ++i) {
    int nr = r4 * 16 + i;                      // local n
    WoT[(size_t)(n0 + nr) * HH + k0 + c] = f2bf(t[c][nr]);
  }
}

// ---------------- dataflow tree-LSTM scan, Wh resident in LDS (bf16)
// grid = 64 slices x ngroups (cooperative). Block (g,s): nodes g, g+ngroups,...;
// owns 8 hidden units (all 4 gates = 32 cols), Wh slice 32KB LDS.
// Sync protocol (fence-free, r5 post-mortem):
//   producers: write-through relaxed u64 atomic stores (visible at MALL),
//              vmcnt(0), relaxed fetch_add on count[node].
//   consumers: relaxed poll of count (bypass), then PLAIN CACHED reads of
//              parent h/c. Safe: slots are write-once + read-after-flag +
//              64B-aligned, kernel boundaries wbinv L2, replays deterministic
//              -> no L2 can hold a pre-write copy. 8 slices/XCD share 1 fetch.
__global__ __launch_bounds__(256, 3) void scan_kernel(
    const int* __restrict__ parent, const float* __restrict__ Wh,
    const float* __restrict__ Xg, float* Hs, float* Cs,
    unsigned short* __restrict__ hs_bf, int* count, int ngroups) {
  int bid = blockIdx.x;
  int s = bid & 63;                        // slice 0..63
  int g = bid >> 6;                        // group 0..ngroups-1
  int tid = threadIdx.x;
  int lc = tid & 31;                       // local col: gate=lc>>3, hid=lc&7
  int kseg = tid >> 5;                     // 0..7, 64 k-values each
  int b_ = tid >> 3, h_ = tid & 7;         // for reduce/cell (tid<64)

  __shared__ __align__(16) unsigned short WhL[32 * 512];  // 32KB [kg 64][lc 32][8]
  __shared__ __align__(16) float phL[BB * HH];            // 16KB [b][512]

  // ---- stage Wh slice once (bf16, tiled for conflict-free b128 reads)
  for (int q = tid; q < 32 * 512; q += 256) {
    int k = q >> 5, c = q & 31;
    int gc = (c >> 3) * HH + s * 8 + (c & 7);
    WhL[((k >> 3) * 32 + c) * 8 + (k & 7)] = f2bf(Wh[(size_t)k * G4 + gc]);
  }
  __syncthreads();

  for (int node = g; node < NN; node += ngroups) {
    int slot = parent[node] + 1;
    // prefetch Xg (depends only on node, overlaps the poll)
    float xg4[4];
    if (tid < 64) {
#pragma unroll
      for (int gt = 0; gt < 4; ++gt)
        xg4[gt] = Xg[(size_t)node * (BB * G4) + (size_t)b_ * G4 + gt * HH + s * 8 + h_];
    }
    // ---- wait for parent: RELAXED poll of one dword (no inv, no wb)
    if (tid == 0 && slot > 0) {
      for (long spin = 0; spin < 300000L; ++spin) {
        int v = __hip_atomic_load(&count[slot - 1], __ATOMIC_RELAXED,
                                  __HIP_MEMORY_SCOPE_AGENT);
        if (v == SLICES) break;
        __builtin_amdgcn_s_sleep(4);
      }
    }
    __syncthreads();

    // ---- stage full parent h: PLAIN CACHED loads (L2-shared across the 8
    // slices of this node on this XCD). 256 thr x 16 floats = 16KB.
    {
      int b = tid >> 5, ko = (tid & 31) * 16;
      const float* src = Hs + (size_t)slot * (BB * HH) + b * HH + ko;
      f32x4* d = (f32x4*)&phL[b * HH + ko];
      d[0] = ((const f32x4*)src)[0];
      d[1] = ((const f32x4*)src)[1];
      d[2] = ((const f32x4*)src)[2];
      d[3] = ((const f32x4*)src)[3];
    }
    __syncthreads();

    float acc[8];
#pragma unroll
    for (int b = 0; b < 8; ++b) acc[b] = 0.f;
    for (int k8 = 0; k8 < 8; ++k8) {
      int kg = kseg * 8 + k8;
      int kloc = kg * 8;                     // = kseg*64 + k8*8
      bf16x8 wv = *(const bf16x8*)&WhL[(kg * 32 + lc) * 8];
      float wf[8];
#pragma unroll
      for (int j = 0; j < 8; ++j) wf[j] = bf2f((unsigned short)wv[j]);
#pragma unroll
      for (int b = 0; b < 8; ++b) {
        const float* pp = &phL[b * HH + kloc];
        f32x4 p0 = *(const f32x4*)pp;
        f32x4 p1 = *(const f32x4*)(pp + 4);
        acc[b] = fmaf(p0[0], wf[0], acc[b]);
        acc[b] = fmaf(p0[1], wf[1], acc[b]);
        acc[b] = fmaf(p0[2], wf[2], acc[b]);
        acc[b] = fmaf(p0[3], wf[3], acc[b]);
        acc[b] = fmaf(p1[0], wf[4], acc[b]);
        acc[b] = fmaf(p1[1], wf[5], acc[b]);
        acc[b] = fmaf(p1[2], wf[6], acc[b]);
        acc[b] = fmaf(p1[3], wf[7], acc[b]);
      }
    }
    __syncthreads();  // all done reading phL
    // ---- write partials (overlay phL: 256 threads x 8 f32 = 8KB)
    {
      float* part = phL;
      *(f32x4*)&part[tid * 8] = (f32x4){acc[0], acc[1], acc[2], acc[3]};
      *(f32x4*)&part[tid * 8 + 4] = (f32x4){acc[4], acc[5], acc[6], acc[7]};
    }
    __syncthreads();
    // ---- reduce over 8 k-segments + LSTM cell (threads 0..63: (b, hid))
    if (tid < 64) {
      const float* part = phL;
      float gsum[4];
#pragma unroll
      for (int gt = 0; gt < 4; ++gt) {
        int lc2 = gt * 8 + h_;
        float sm = xg4[gt];
#pragma unroll
        for (int q = 0; q < 8; ++q) sm += part[(q * 32 + lc2) * 8 + b_];
        gsum[gt] = sm;
      }
      int hidx = s * 8 + h_;
      float pc = Cs[(size_t)slot * (BB * HH) + b_ * HH + hidx];  // cached read
      float c = sigm(gsum[1]) * pc + sigm(gsum[0]) * tanhf(gsum[3]);
      float h = sigm(gsum[2]) * tanhf(c);
      size_t oi = (size_t)(node + 1) * (BB * HH) + b_ * HH + hidx;
      // pack (h_, h_+1) into one u64 write-through atomic (halves atomic ops)
      float c1 = __shfl_down(c, 1);
      float h1 = __shfl_down(h, 1);
      if ((h_ & 1) == 0) {
        unsigned long long cu =
            (((unsigned long long)__float_as_uint(c1)) << 32) | __float_as_uint(c);
        unsigned long long hu =
            (((unsigned long long)__float_as_uint(h1)) << 32) | __float_as_uint(h);
        __hip_atomic_store((unsigned long long*)&Cs[oi], cu, __ATOMIC_RELAXED,
                           __HIP_MEMORY_SCOPE_AGENT);
        __hip_atomic_store((unsigned long long*)&Hs[oi], hu, __ATOMIC_RELAXED,
                           __HIP_MEMORY_SCOPE_AGENT);
      }
      hs_bf[((size_t)b_ * NN + node) * HH + hidx] = f2bf(h);  // normal store
    }
    // publish: wave 0 made all the data stores; drain them, then bump count.
    if (tid == 0) {
      asm volatile("s_waitcnt vmcnt(0)" ::: "memory");
      __hip_atomic_fetch_add(&count[node], 1, __ATOMIC_RELAXED,
                             __HIP_MEMORY_SCOPE_AGENT);
    }
    __syncthreads();
  }
}

// ---------------- logits = hs_bf (2048x512) @ WoT^T (32000x512) + bo, f32 out
__global__ __launch_bounds__(256) void gemm_kernel(
    const unsigned short* __restrict__ A, const unsigned short* __restrict__ Bt,
    const float* __restrict__ bo, float* __restrict__ C) {
  int bid = blockIdx.x;                    // 0..3999
  int swz = (bid & 7) * 500 + (bid >> 3);  // XCD-contiguous chunks
  int nt = swz >> 4;                       // 0..249
  int mt = swz & 15;                       // 0..15
  int tid = threadIdx.x;
  int wave = tid >> 6;
  int lane = tid & 63;
  int wr = wave >> 1, wc = wave & 1;
  int lr = lane & 15, lh = lane >> 4;
  __shared__ __align__(16) unsigned short Al[128 * 32];
  __shared__ __align__(16) unsigned short Bl[128 * 32];
  int m0 = mt * 128, n0 = nt * 128;
  f32x4 acc[4][4];
#pragma unroll
  for (int i = 0; i < 4; ++i)
#pragma unroll
    for (int j = 0; j < 4; ++j) acc[i][j] = (f32x4){0.f, 0.f, 0.f, 0.f};

  for (int k0 = 0; k0 < HH; k0 += 32) {
#pragma unroll
    for (int q = 0; q < 2; ++q) {
      int off = wave * 2048 + q * 1024 + lane * 16;
      int r = off >> 6;
      int cb = off & 63;
      const unsigned short* ga = A + (size_t)(m0 + r) * HH + k0 + (cb >> 1);
      const unsigned short* gb = Bt + (size_t)(n0 + r) * HH + k0 + (cb >> 1);
      __builtin_amdgcn_global_load_lds(
          (const __attribute__((address_space(1))) unsigned int*)ga,
          (__attribute__((address_space(3))) unsigned int*)((char*)Al + wave * 2048 + q * 1024),
          16, 0, 0);
      __builtin_amdgcn_global_load_lds(
          (const __attribute__((address_space(1))) unsigned int*)gb,
          (__attribute__((address_space(3))) unsigned int*)((char*)Bl + wave * 2048 + q * 1024),
          16, 0, 0);
    }
    __syncthreads();
    bf16x8 af[4], bfr[4];
#pragma unroll
    for (int i = 0; i < 4; ++i) {
      af[i] = *(const bf16x8*)&Al[(wr * 64 + i * 16 + lr) * 32 + lh * 8];
      bfr[i] = *(const bf16x8*)&Bl[(wc * 64 + i * 16 + lr) * 32 + lh * 8];
    }
#pragma unroll
    for (int i = 0; i < 4; ++i)
#pragma unroll
      for (int j = 0; j < 4; ++j)
        acc[i][j] = __builtin_amdgcn_mfma_f32_16x16x32_bf16(af[i], bfr[j], acc[i][j], 0, 0, 0);
    __syncthreads();
  }
#pragma unroll
  for (int j = 0; j < 4; ++j) {
    int v = n0 + wc * 64 + j * 16 + lr;
    float bias = bo[v];
#pragma unroll
    for (int i = 0; i < 4; ++i) {
#pragma unroll
      for (int r2 = 0; r2 < 4; ++r2) {
        int m = m0 + wr * 64 + i * 16 + lh * 4 + r2;
        C[(size_t)m * VV + v] = acc[i][j][r2] + bias;
      }
    }
  }
}

// ---------------- workspace layout (bytes)
static const size_t OFF_COUNT = 0;                       // 256*4 = 1024 (pad 4096)
static const size_t OFF_HS = 4096;                       // 257*8*512*4 = 4210688
static const size_t OFF_CS = OFF_HS + 4210688;           // 4214784
static const size_t OFF_XG = OFF_CS + 4210688;           // 8425472, 16777216 B
static const size_t OFF_HSBF = OFF_XG + 16777216;        // 25202688, 2097152 B
static const size_t OFF_WOT = OFF_HSBF + 2097152;        // 27299840, 32768000 B
// total = 60,067,840 bytes

extern "C" void kernel_launch(void* const* d_in, const int* in_sizes, int n_in,
                              void* d_out, int out_size, void* d_ws, size_t ws_size,
                              hipStream_t stream) {
  const int* rel_ids = (const int*)d_in[0];
  const int* sent_ids = (const int*)d_in[1];
  const int* parent = (const int*)d_in[2];
  const float* root_h = (const float*)d_in[3];
  const float* word_emb = (const float*)d_in[4];
  const float* rel_emb = (const float*)d_in[5];
  const float* Wx = (const float*)d_in[6];
  const float* Wh = (const float*)d_in[7];
  const float* bias = (const float*)d_in[8];
  const float* Wo = (const float*)d_in[9];
  const float* bo = (const float*)d_in[10];
  float* out = (float*)d_out;

  char* ws = (char*)d_ws;
  int* count = (int*)(ws + OFF_COUNT);
  float* Hs = (float*)(ws + OFF_HS);
  float* Cs = (float*)(ws + OFF_CS);
  float* Xg = (float*)(ws + OFF_XG);
  unsigned short* hs_bf = (unsigned short*)(ws + OFF_HSBF);
  unsigned short* WoT = (unsigned short*)(ws + OFF_WOT);

  hipMemsetAsync(ws, 0, 4096, stream);  // per-node completion counters
  init_kernel<<<16, 256, 0, stream>>>(root_h, Hs, Cs);
  xg_kernel<<<dim3(8, 256), 256, 0, stream>>>(rel_ids, sent_ids, parent, word_emb,
                                              rel_emb, Wx, bias, Xg);
  wot_kernel<<<dim3(500, 8), 256, 0, stream>>>(Wo, WoT);
  {
    int ng = 12;  // 64 slices x 12 groups = 768 blocks (3 blocks/CU @ 48KB LDS)
    void* args[] = {(void*)&parent, (void*)&Wh, (void*)&Xg, (void*)&Hs,
                    (void*)&Cs, (void*)&hs_bf, (void*)&count, (void*)&ng};
    hipError_t e = hipLaunchCooperativeKernel((void*)scan_kernel, dim3(64 * 12),
                                              dim3(256), args, 0, stream);
    if (e != hipSuccess) {
      ng = 8;  // 512 blocks (2 blocks/CU)
      e = hipLaunchCooperativeKernel((void*)scan_kernel, dim3(64 * 8), dim3(256),
                                     args, 0, stream);
      if (e != hipSuccess) {
        // last resort: plain launch (watchdog-bounded, 512 blocks fit 2/CU)
        scan_kernel<<<512, 256, 0, stream>>>(parent, Wh, Xg, Hs, Cs, hs_bf, count, 8);
      }
    }
  }
  gemm_kernel<<<4000, 256, 0, stream>>>(hs_bf, WoT, bo, out);
}

// Round 7
// 1443.013 us; speedup vs baseline: 1.3484x; 1.3484x over previous
//
#include <hip/hip_runtime.h>
#include <hip/hip_bf16.h>
#include <stdint.h>

#define BB 8
#define NN 256
#define HH 512
#define G4 2048       // 4*HH
#define EE 512
#define RDIM 64
#define KX 576        // RDIM + EE
#define VV 32000
#define SLICES 64     // 64 hidden-slices of 8 units (x4 gates = 32 cols)

using f32x4 = __attribute__((ext_vector_type(4))) float;
using bf16x8 = __attribute__((ext_vector_type(8))) short;

__device__ __forceinline__ unsigned short f2bf(float f) {
  unsigned int u = __float_as_uint(f);
  u = (u + 0x7FFFu + ((u >> 16) & 1u)) >> 16;
  return (unsigned short)u;
}
__device__ __forceinline__ float bf2f(unsigned short s) {
  return __uint_as_float(((unsigned int)s) << 16);
}
__device__ __forceinline__ float sigm(float x) { return 1.0f / (1.0f + __expf(-x)); }

// ---------------- init: Hs16[0]=bf16(root_h), Cs[0]=root_h (ref: Cs0 = Hs0)
__global__ void init_kernel(const float* __restrict__ root_h,
                            unsigned short* __restrict__ Hs16,
                            float* __restrict__ Cs) {
  int i = blockIdx.x * 256 + threadIdx.x;   // 0..4095
  float v = root_h[i];
  Hs16[i] = f2bf(v);
  Cs[i] = v;
}

// ---------------- level schedule: order[] = nodes sorted level-major (stable)
__global__ __launch_bounds__(64) void levels_kernel(const int* __restrict__ parent,
                                                    int* __restrict__ order) {
  __shared__ int dep[NN];
  __shared__ int cnt[NN];
  int tid = threadIdx.x;
  for (int i = tid; i < NN; i += 64) cnt[i] = 0;
  __syncthreads();
  if (tid == 0) {
    for (int i = 0; i < NN; ++i) {
      int p = parent[i];
      int d = (p < 0) ? 0 : dep[p] + 1;
      dep[i] = d;
      cnt[d]++;
    }
    int run = 0;
    for (int d = 0; d < NN; ++d) { int c = cnt[d]; cnt[d] = run; run += c; }
    for (int i = 0; i < NN; ++i) order[cnt[dep[i]]++] = i;
  }
}

// ---------------- Xg = concat(rel_emb[rel], word_emb[pword]) @ Wx + b
// grid (8 colblocks, 256 nodes), 256 threads. Xg layout [n][b][2048]
__global__ __launch_bounds__(256) void xg_kernel(
    const int* __restrict__ rel_ids, const int* __restrict__ sent_ids,
    const int* __restrict__ parent, const float* __restrict__ word_emb,
    const float* __restrict__ rel_emb, const float* __restrict__ Wx,
    const float* __restrict__ bias, float* __restrict__ Xg) {
  int n = blockIdx.y;
  int cb = blockIdx.x;
  int tid = threadIdx.x;
  __shared__ float xs[BB * KX];     // [b][k], k contiguous
  int par = parent[n];
  int b = tid >> 5;
  int l32 = tid & 31;
  int rid = rel_ids[b * NN + n];
  int pw = (par < 0) ? 0 : sent_ids[b * NN + par];   // SOS = 0
  const float* re = rel_emb + (size_t)rid * RDIM;
  const float* we = word_emb + (size_t)pw * EE;
  for (int q = l32; q < RDIM; q += 32) xs[b * KX + q] = re[q];
  for (int q = l32; q < EE; q += 32) xs[b * KX + RDIM + q] = we[q];
  __syncthreads();
  int col = cb * 256 + tid;
  float bb = bias[col];
  float acc[BB];
#pragma unroll
  for (int i = 0; i < BB; ++i) acc[i] = bb;
  const float* wxp = Wx + col;
  for (int k = 0; k < KX; k += 4) {
    float w0 = wxp[(size_t)(k + 0) * G4];
    float w1 = wxp[(size_t)(k + 1) * G4];
    float w2 = wxp[(size_t)(k + 2) * G4];
    float w3 = wxp[(size_t)(k + 3) * G4];
#pragma unroll
    for (int i = 0; i < BB; ++i) {
      f32x4 p = *(const f32x4*)&xs[i * KX + k];  // uniform broadcast
      acc[i] = fmaf(p[0], w0, acc[i]);
      acc[i] = fmaf(p[1], w1, acc[i]);
      acc[i] = fmaf(p[2], w2, acc[i]);
      acc[i] = fmaf(p[3], w3, acc[i]);
    }
  }
  float* xgout = Xg + (size_t)n * (BB * G4) + col;
#pragma unroll
  for (int i = 0; i < BB; ++i) xgout[(size_t)i * G4] = acc[i];
}

// ---------------- Wo (512 x 32000) f32  ->  WoT (32000 x 512) bf16
__global__ __launch_bounds__(256) void wot_kernel(const float* __restrict__ Wo,
                                                  unsigned short* __restrict__ WoT) {
  __shared__ float t[64][65];
  int n0 = blockIdx.x * 64;
  int k0 = blockIdx.y * 64;
  int tid = threadIdx.x;
  int c = tid & 63;
  int r4 = tid >> 6;
#pragma unroll
  for (int i = 0; i < 16; ++i) {
    int r = r4 * 16 + i;                       // local k
    t[r][c] = Wo[(size_t)(k0 + r) * VV + n0 + c];
  }
  __syncthreads();
#pragma unroll
  for (int i = 0; i < 16; ++i) {
    int nr = r4 * 16 + i;                      // local n
    WoT[(size_t)(n0 + nr) * HH + k0 + c] = f2bf(t[c][nr]);
  }
}

// ---------------- dataflow tree-LSTM scan, Wh resident in LDS (bf16)
// grid = 64 slices x ngroups (cooperative). Block (g,s) walks order[] (level-
// major node schedule -> no head-of-line blocking); owns 8 hidden units.
// Memory protocol = round 5's proven fence-free form, verbatim:
//   producers: relaxed DWORD write-through atomic stores, vmcnt(0),
//              relaxed fetch_add on count[node].
//   consumers: relaxed poll of count dword, relaxed u64 bypass loads of
//              parent h (bf16) / c (f32). No acquire/release anywhere.
__global__ __launch_bounds__(256, 3) void scan_kernel(
    const int* __restrict__ parent, const float* __restrict__ Wh,
    const float* __restrict__ Xg, unsigned short* Hs16, float* Cs,
    unsigned short* __restrict__ hs_bf, const int* __restrict__ order,
    int* count, int ngroups) {
  int bid = blockIdx.x;
  int s = bid & 63;                        // slice 0..63
  int g = bid >> 6;                        // group 0..ngroups-1
  int tid = threadIdx.x;
  int lc = tid & 31;                       // local col: gate=lc>>3, hid=lc&7
  int kseg = tid >> 5;                     // 0..7, 64 k-values each
  int b_ = tid >> 3, h_ = tid & 7;         // for reduce/cell (tid<64)

  __shared__ __align__(16) unsigned short WhL[32 * 512];  // 32KB [kg 64][lc 32][8]
  __shared__ __align__(16) float phL[BB * HH];            // 16KB [b][512]

  // ---- stage Wh slice once (bf16, tiled for conflict-free b128 reads)
  for (int q = tid; q < 32 * 512; q += 256) {
    int k = q >> 5, c = q & 31;
    int gc = (c >> 3) * HH + s * 8 + (c & 7);
    WhL[((k >> 3) * 32 + c) * 8 + (k & 7)] = f2bf(Wh[(size_t)k * G4 + gc]);
  }
  __syncthreads();

  for (int idx = g; idx < NN; idx += ngroups) {
    int node = order[idx];
    int slot = parent[node] + 1;
    // prefetch Xg (depends only on node, overlaps the poll)
    float xg4[4];
    if (tid < 64) {
#pragma unroll
      for (int gt = 0; gt < 4; ++gt)
        xg4[gt] = Xg[(size_t)node * (BB * G4) + (size_t)b_ * G4 + gt * HH + s * 8 + h_];
    }
    // ---- wait for parent: RELAXED poll of one dword (no inv, no wb)
    if (tid == 0 && slot > 0) {
      for (long spin = 0; spin < 300000L; ++spin) {
        int v = __hip_atomic_load(&count[slot - 1], __ATOMIC_RELAXED,
                                  __HIP_MEMORY_SCOPE_AGENT);
        if (v == SLICES) break;
        __builtin_amdgcn_s_sleep(4);
      }
    }
    __syncthreads();

    // ---- stage parent h (bf16): relaxed u64 bypass loads, 8KB per block.
    {
      int b = tid >> 5, ko = (tid & 31) * 16;
      const unsigned long long* src =
          (const unsigned long long*)(Hs16 + (size_t)slot * (BB * HH) + b * HH + ko);
      float* d = &phL[b * HH + ko];
#pragma unroll
      for (int j = 0; j < 4; ++j) {
        unsigned long long v = __hip_atomic_load(&src[j], __ATOMIC_RELAXED,
                                                 __HIP_MEMORY_SCOPE_AGENT);
        d[4 * j + 0] = bf2f((unsigned short)v);
        d[4 * j + 1] = bf2f((unsigned short)(v >> 16));
        d[4 * j + 2] = bf2f((unsigned short)(v >> 32));
        d[4 * j + 3] = bf2f((unsigned short)(v >> 48));
      }
    }
    __syncthreads();

    float acc[8];
#pragma unroll
    for (int b = 0; b < 8; ++b) acc[b] = 0.f;
    for (int k8 = 0; k8 < 8; ++k8) {
      int kg = kseg * 8 + k8;
      int kloc = kg * 8;                     // = kseg*64 + k8*8
      bf16x8 wv = *(const bf16x8*)&WhL[(kg * 32 + lc) * 8];
      float wf[8];
#pragma unroll
      for (int j = 0; j < 8; ++j) wf[j] = bf2f((unsigned short)wv[j]);
#pragma unroll
      for (int b = 0; b < 8; ++b) {
        const float* pp = &phL[b * HH + kloc];
        f32x4 p0 = *(const f32x4*)pp;
        f32x4 p1 = *(const f32x4*)(pp + 4);
        acc[b] = fmaf(p0[0], wf[0], acc[b]);
        acc[b] = fmaf(p0[1], wf[1], acc[b]);
        acc[b] = fmaf(p0[2], wf[2], acc[b]);
        acc[b] = fmaf(p0[3], wf[3], acc[b]);
        acc[b] = fmaf(p1[0], wf[4], acc[b]);
        acc[b] = fmaf(p1[1], wf[5], acc[b]);
        acc[b] = fmaf(p1[2], wf[6], acc[b]);
        acc[b] = fmaf(p1[3], wf[7], acc[b]);
      }
    }
    __syncthreads();  // all done reading phL
    // ---- write partials (overlay phL: 256 threads x 8 f32 = 8KB)
    {
      float* part = phL;
      *(f32x4*)&part[tid * 8] = (f32x4){acc[0], acc[1], acc[2], acc[3]};
      *(f32x4*)&part[tid * 8 + 4] = (f32x4){acc[4], acc[5], acc[6], acc[7]};
    }
    __syncthreads();
    // ---- reduce over 8 k-segments + LSTM cell (threads 0..63: (b, hid))
    if (tid < 64) {
      const float* part = phL;
      float gsum[4];
#pragma unroll
      for (int gt = 0; gt < 4; ++gt) {
        int lc2 = gt * 8 + h_;
        float sm = xg4[gt];
#pragma unroll
        for (int q = 0; q < 8; ++q) sm += part[(q * 32 + lc2) * 8 + b_];
        gsum[gt] = sm;
      }
      int hidx = s * 8 + h_;
      float pc = __hip_atomic_load(&Cs[(size_t)slot * (BB * HH) + b_ * HH + hidx],
                                   __ATOMIC_RELAXED, __HIP_MEMORY_SCOPE_AGENT);
      float c = sigm(gsum[1]) * pc + sigm(gsum[0]) * tanhf(gsum[3]);
      float h = sigm(gsum[2]) * tanhf(c);
      size_t oi = (size_t)(node + 1) * (BB * HH) + b_ * HH + hidx;
      // Cs: f32 dword write-through atomic (r5-proven form)
      __hip_atomic_store(&Cs[oi], c, __ATOMIC_RELAXED, __HIP_MEMORY_SCOPE_AGENT);
      // Hs16 + hs_bf: pack (h_, h_+1) bf16 pair -> one dword each
      unsigned short hb = f2bf(h);
      unsigned short hb1 = (unsigned short)__shfl_down((int)hb, 1);
      if ((h_ & 1) == 0) {
        unsigned int hp = ((unsigned int)hb1 << 16) | hb;
        __hip_atomic_store((unsigned int*)&Hs16[oi], hp, __ATOMIC_RELAXED,
                           __HIP_MEMORY_SCOPE_AGENT);
        *(unsigned int*)&hs_bf[((size_t)b_ * NN + node) * HH + hidx] = hp;
      }
    }
    // publish: wave 0 made all the data stores; drain them, then bump count.
    if (tid == 0) {
      asm volatile("s_waitcnt vmcnt(0)" ::: "memory");
      __hip_atomic_fetch_add(&count[node], 1, __ATOMIC_RELAXED,
                             __HIP_MEMORY_SCOPE_AGENT);
    }
    __syncthreads();
  }
}

// ---------------- logits = hs_bf (2048x512) @ WoT^T (32000x512) + bo, f32 out
__global__ __launch_bounds__(256) void gemm_kernel(
    const unsigned short* __restrict__ A, const unsigned short* __restrict__ Bt,
    const float* __restrict__ bo, float* __restrict__ C) {
  int bid = blockIdx.x;                    // 0..3999
  int swz = (bid & 7) * 500 + (bid >> 3);  // XCD-contiguous chunks
  int nt = swz >> 4;                       // 0..249
  int mt = swz & 15;                       // 0..15
  int tid = threadIdx.x;
  int wave = tid >> 6;
  int lane = tid & 63;
  int wr = wave >> 1, wc = wave & 1;
  int lr = lane & 15, lh = lane >> 4;
  __shared__ __align__(16) unsigned short Al[128 * 32];
  __shared__ __align__(16) unsigned short Bl[128 * 32];
  int m0 = mt * 128, n0 = nt * 128;
  f32x4 acc[4][4];
#pragma unroll
  for (int i = 0; i < 4; ++i)
#pragma unroll
    for (int j = 0; j < 4; ++j) acc[i][j] = (f32x4){0.f, 0.f, 0.f, 0.f};

  for (int k0 = 0; k0 < HH; k0 += 32) {
#pragma unroll
    for (int q = 0; q < 2; ++q) {
      int off = wave * 2048 + q * 1024 + lane * 16;
      int r = off >> 6;
      int cb = off & 63;
      const unsigned short* ga = A + (size_t)(m0 + r) * HH + k0 + (cb >> 1);
      const unsigned short* gb = Bt + (size_t)(n0 + r) * HH + k0 + (cb >> 1);
      __builtin_amdgcn_global_load_lds(
          (const __attribute__((address_space(1))) unsigned int*)ga,
          (__attribute__((address_space(3))) unsigned int*)((char*)Al + wave * 2048 + q * 1024),
          16, 0, 0);
      __builtin_amdgcn_global_load_lds(
          (const __attribute__((address_space(1))) unsigned int*)gb,
          (__attribute__((address_space(3))) unsigned int*)((char*)Bl + wave * 2048 + q * 1024),
          16, 0, 0);
    }
    __syncthreads();
    bf16x8 af[4], bfr[4];
#pragma unroll
    for (int i = 0; i < 4; ++i) {
      af[i] = *(const bf16x8*)&Al[(wr * 64 + i * 16 + lr) * 32 + lh * 8];
      bfr[i] = *(const bf16x8*)&Bl[(wc * 64 + i * 16 + lr) * 32 + lh * 8];
    }
#pragma unroll
    for (int i = 0; i < 4; ++i)
#pragma unroll
      for (int j = 0; j < 4; ++j)
        acc[i][j] = __builtin_amdgcn_mfma_f32_16x16x32_bf16(af[i], bfr[j], acc[i][j], 0, 0, 0);
    __syncthreads();
  }
#pragma unroll
  for (int j = 0; j < 4; ++j) {
    int v = n0 + wc * 64 + j * 16 + lr;
    float bias = bo[v];
#pragma unroll
    for (int i = 0; i < 4; ++i) {
#pragma unroll
      for (int r2 = 0; r2 < 4; ++r2) {
        int m = m0 + wr * 64 + i * 16 + lh * 4 + r2;
        C[(size_t)m * VV + v] = acc[i][j][r2] + bias;
      }
    }
  }
}

// ---------------- workspace layout (bytes)
static const size_t OFF_COUNT = 0;                       // int[256] = 1024
static const size_t OFF_ORDER = 1024;                    // int[256] = 1024 (pad 4096)
static const size_t OFF_HS16 = 4096;                     // 257*8*512*2 = 2105344
static const size_t OFF_CS = OFF_HS16 + 2105344;         // 2109440, 4210688 B
static const size_t OFF_XG = OFF_CS + 4210688;           // 6320128, 16777216 B
static const size_t OFF_HSBF = OFF_XG + 16777216;        // 23097344, 2097152 B
static const size_t OFF_WOT = OFF_HSBF + 2097152;        // 25194496, 32768000 B
// total = 57,962,496 bytes

extern "C" void kernel_launch(void* const* d_in, const int* in_sizes, int n_in,
                              void* d_out, int out_size, void* d_ws, size_t ws_size,
                              hipStream_t stream) {
  const int* rel_ids = (const int*)d_in[0];
  const int* sent_ids = (const int*)d_in[1];
  const int* parent = (const int*)d_in[2];
  const float* root_h = (const float*)d_in[3];
  const float* word_emb = (const float*)d_in[4];
  const float* rel_emb = (const float*)d_in[5];
  const float* Wx = (const float*)d_in[6];
  const float* Wh = (const float*)d_in[7];
  const float* bias = (const float*)d_in[8];
  const float* Wo = (const float*)d_in[9];
  const float* bo = (const float*)d_in[10];
  float* out = (float*)d_out;

  char* ws = (char*)d_ws;
  int* count = (int*)(ws + OFF_COUNT);
  int* order = (int*)(ws + OFF_ORDER);
  unsigned short* Hs16 = (unsigned short*)(ws + OFF_HS16);
  float* Cs = (float*)(ws + OFF_CS);
  float* Xg = (float*)(ws + OFF_XG);
  unsigned short* hs_bf = (unsigned short*)(ws + OFF_HSBF);
  unsigned short* WoT = (unsigned short*)(ws + OFF_WOT);

  hipMemsetAsync(ws, 0, 4096, stream);  // per-node completion counters
  init_kernel<<<16, 256, 0, stream>>>(root_h, Hs16, Cs);
  levels_kernel<<<1, 64, 0, stream>>>(parent, order);
  xg_kernel<<<dim3(8, 256), 256, 0, stream>>>(rel_ids, sent_ids, parent, word_emb,
                                              rel_emb, Wx, bias, Xg);
  wot_kernel<<<dim3(500, 8), 256, 0, stream>>>(Wo, WoT);
  {
    int ng = 12;  // 64 slices x 12 groups = 768 blocks (3 blocks/CU @ 48KB LDS)
    void* args[] = {(void*)&parent, (void*)&Wh, (void*)&Xg, (void*)&Hs16,
                    (void*)&Cs, (void*)&hs_bf, (void*)&order, (void*)&count,
                    (void*)&ng};
    hipError_t e = hipLaunchCooperativeKernel((void*)scan_kernel, dim3(64 * 12),
                                              dim3(256), args, 0, stream);
    if (e != hipSuccess) {
      ng = 8;  // 512 blocks (2 blocks/CU)
      e = hipLaunchCooperativeKernel((void*)scan_kernel, dim3(64 * 8), dim3(256),
                                     args, 0, stream);
      if (e != hipSuccess) {
        // last resort: plain launch (watchdog-bounded, 512 blocks fit)
        scan_kernel<<<512, 256, 0, stream>>>(parent, Wh, Xg, Hs16, Cs, hs_bf,
                                             order, count, 8);
      }
    }
  }
  gemm_kernel<<<4000, 256, 0, stream>>>(hs_bf, WoT, bo, out);
}

// Round 9
// 757.506 us; speedup vs baseline: 2.5687x; 1.9050x over previous
//
#include <hip/hip_runtime.h>
#include <hip/hip_bf16.h>
#include <stdint.h>

#define BB 8
#define NN 256
#define HH 512
#define G4 2048       // 4*HH
#define EE 512
#define RDIM 64
#define KX 576        // RDIM + EE
#define VV 32000
#define SLICES 64     // 64 hidden-slices of 8 units (x4 gates = 32 cols)
#define CSTRIDE 16    // count[] padded to 64B/node (MALL sector decontention)

using f32x4 = __attribute__((ext_vector_type(4))) float;
using bf16x8 = __attribute__((ext_vector_type(8))) short;

__device__ __forceinline__ unsigned short f2bf(float f) {
  unsigned int u = __float_as_uint(f);
  u = (u + 0x7FFFu + ((u >> 16) & 1u)) >> 16;
  return (unsigned short)u;
}
__device__ __forceinline__ float bf2f(unsigned short s) {
  return __uint_as_float(((unsigned int)s) << 16);
}
__device__ __forceinline__ float sigm(float x) { return 1.0f / (1.0f + __expf(-x)); }

// ---------------- init: Hs[0]=root_h, Cs[0]=root_h (ref: Cs0 = Hs0)
__global__ void init_kernel(const float* __restrict__ root_h, float* __restrict__ Hs,
                            float* __restrict__ Cs) {
  int i = blockIdx.x * 256 + threadIdx.x;   // 0..4095
  float v = root_h[i];
  Hs[i] = v;
  Cs[i] = v;
}

// ---------------- level schedule: order[] = nodes sorted level-major (stable)
__global__ __launch_bounds__(64) void levels_kernel(const int* __restrict__ parent,
                                                    int* __restrict__ order) {
  __shared__ int dep[NN];
  __shared__ int cnt[NN];
  int tid = threadIdx.x;
  for (int i = tid; i < NN; i += 64) cnt[i] = 0;
  __syncthreads();
  if (tid == 0) {
    for (int i = 0; i < NN; ++i) {
      int p = parent[i];
      int d = (p < 0) ? 0 : dep[p] + 1;
      dep[i] = d;
      cnt[d]++;
    }
    int run = 0;
    for (int d = 0; d < NN; ++d) { int c = cnt[d]; cnt[d] = run; run += c; }
    for (int i = 0; i < NN; ++i) order[cnt[dep[i]]++] = i;
  }
}

// ---------------- Xg = concat(rel_emb[rel], word_emb[pword]) @ Wx + b
// grid (8 colblocks, 256 nodes), 256 threads. Xg layout [n][b][2048]
__global__ __launch_bounds__(256) void xg_kernel(
    const int* __restrict__ rel_ids, const int* __restrict__ sent_ids,
    const int* __restrict__ parent, const float* __restrict__ word_emb,
    const float* __restrict__ rel_emb, const float* __restrict__ Wx,
    const float* __restrict__ bias, float* __restrict__ Xg) {
  int n = blockIdx.y;
  int cb = blockIdx.x;
  int tid = threadIdx.x;
  __shared__ float xs[BB * KX];     // [b][k], k contiguous
  int par = parent[n];
  int b = tid >> 5;
  int l32 = tid & 31;
  int rid = rel_ids[b * NN + n];
  int pw = (par < 0) ? 0 : sent_ids[b * NN + par];   // SOS = 0
  const float* re = rel_emb + (size_t)rid * RDIM;
  const float* we = word_emb + (size_t)pw * EE;
  for (int q = l32; q < RDIM; q += 32) xs[b * KX + q] = re[q];
  for (int q = l32; q < EE; q += 32) xs[b * KX + RDIM + q] = we[q];
  __syncthreads();
  int col = cb * 256 + tid;
  float bb = bias[col];
  float acc[BB];
#pragma unroll
  for (int i = 0; i < BB; ++i) acc[i] = bb;
  const float* wxp = Wx + col;
  for (int k = 0; k < KX; k += 4) {
    float w0 = wxp[(size_t)(k + 0) * G4];
    float w1 = wxp[(size_t)(k + 1) * G4];
    float w2 = wxp[(size_t)(k + 2) * G4];
    float w3 = wxp[(size_t)(k + 3) * G4];
#pragma unroll
    for (int i = 0; i < BB; ++i) {
      f32x4 p = *(const f32x4*)&xs[i * KX + k];  // uniform broadcast
      acc[i] = fmaf(p[0], w0, acc[i]);
      acc[i] = fmaf(p[1], w1, acc[i]);
      acc[i] = fmaf(p[2], w2, acc[i]);
      acc[i] = fmaf(p[3], w3, acc[i]);
    }
  }
  float* xgout = Xg + (size_t)n * (BB * G4) + col;
#pragma unroll
  for (int i = 0; i < BB; ++i) xgout[(size_t)i * G4] = acc[i];
}

// ---------------- Wo (512 x 32000) f32  ->  WoT (32000 x 512) bf16
__global__ __launch_bounds__(256) void wot_kernel(const float* __restrict__ Wo,
                                                  unsigned short* __restrict__ WoT) {
  __shared__ float t[64][65];
  int n0 = blockIdx.x * 64;
  int k0 = blockIdx.y * 64;
  int tid = threadIdx.x;
  int c = tid & 63;
  int r4 = tid >> 6;
#pragma unroll
  for (int i = 0; i < 16; ++i) {
    int r = r4 * 16 + i;                       // local k
    t[r][c] = Wo[(size_t)(k0 + r) * VV + n0 + c];
  }
  __syncthreads();
#pragma unroll
  for (int i = 0; i < 16; ++i) {
    int nr = r4 * 16 + i;                      // local n
    WoT[(size_t)(n0 + nr) * HH + k0 + c] = f2bf(t[c][nr]);
  }
}

// ---------------- dataflow tree-LSTM scan, Wh resident in LDS (bf16)
// grid = 64 slices x ngroups (cooperative). Block (g,s) walks order[] (level-
// major schedule). Memory protocol = round 5's proven fence-free form verbatim.
// Hardening: bounded spin + global abort flag -> a stall costs ~60ms and one
// absmax failure, never a dead container.
__global__ __launch_bounds__(256, 3) void scan_kernel(
    const int* __restrict__ parent, const float* __restrict__ Wh,
    const float* __restrict__ Xg, float* Hs, float* Cs,
    unsigned short* __restrict__ hs_bf, const int* __restrict__ order,
    int* count, int* abortf, int ngroups) {
  int bid = blockIdx.x;
  int s = bid & 63;                        // slice 0..63
  int g = bid >> 6;                        // group 0..ngroups-1
  int tid = threadIdx.x;
  int lc = tid & 31;                       // local col: gate=lc>>3, hid=lc&7
  int kseg = tid >> 5;                     // 0..7, 64 k-values each
  int b_ = tid >> 3, h_ = tid & 7;         // for reduce/cell (tid<64)

  __shared__ __align__(16) unsigned short WhL[32 * 512];  // 32KB [kg 64][lc 32][8]
  __shared__ __align__(16) float phL[BB * HH];            // 16KB [b][512]

  // ---- stage Wh slice once (bf16, tiled for conflict-free b128 reads)
  for (int q = tid; q < 32 * 512; q += 256) {
    int k = q >> 5, c = q & 31;
    int gc = (c >> 3) * HH + s * 8 + (c & 7);
    WhL[((k >> 3) * 32 + c) * 8 + (k & 7)] = f2bf(Wh[(size_t)k * G4 + gc]);
  }
  __syncthreads();

  for (int idx = g; idx < NN; idx += ngroups) {
    int node = order[idx];
    int slot = parent[node] + 1;
    // prefetch Xg (depends only on node, overlaps the poll)
    float xg4[4];
    if (tid < 64) {
#pragma unroll
      for (int gt = 0; gt < 4; ++gt)
        xg4[gt] = Xg[(size_t)node * (BB * G4) + (size_t)b_ * G4 + gt * HH + s * 8 + h_];
    }
    // ---- wait for parent: RELAXED poll of one padded dword + abort check
    if (tid == 0 && slot > 0) {
      int v = 0;
      for (long spin = 0; spin < 150000L; ++spin) {
        v = __hip_atomic_load(&count[(size_t)(slot - 1) * CSTRIDE],
                              __ATOMIC_RELAXED, __HIP_MEMORY_SCOPE_AGENT);
        if (v == SLICES) break;
        if ((spin & 1023) == 1023) {
          if (__hip_atomic_load(abortf, __ATOMIC_RELAXED,
                                __HIP_MEMORY_SCOPE_AGENT) != 0) break;
        }
        __builtin_amdgcn_s_sleep(2);
      }
      if (v != SLICES) {
        __hip_atomic_store(abortf, 1, __ATOMIC_RELAXED, __HIP_MEMORY_SCOPE_AGENT);
      }
    }
    __syncthreads();

    // ---- stage full parent h: relaxed u64 bypass loads (r5 form), 16KB.
    {
      int b = tid >> 5, ko = (tid & 31) * 16;
      unsigned long long* src =
          (unsigned long long*)(Hs + (size_t)slot * (BB * HH) + b * HH + ko);
      float* d = &phL[b * HH + ko];
#pragma unroll
      for (int j = 0; j < 8; ++j) {
        unsigned long long v = __hip_atomic_load(&src[j], __ATOMIC_RELAXED,
                                                 __HIP_MEMORY_SCOPE_AGENT);
        d[2 * j] = __uint_as_float((unsigned int)v);
        d[2 * j + 1] = __uint_as_float((unsigned int)(v >> 32));
      }
    }
    __syncthreads();

    float acc[8];
#pragma unroll
    for (int b = 0; b < 8; ++b) acc[b] = 0.f;
    for (int k8 = 0; k8 < 8; ++k8) {
      int kg = kseg * 8 + k8;
      int kloc = kg * 8;                     // = kseg*64 + k8*8
      bf16x8 wv = *(const bf16x8*)&WhL[(kg * 32 + lc) * 8];
      float wf[8];
#pragma unroll
      for (int j = 0; j < 8; ++j) wf[j] = bf2f((unsigned short)wv[j]);
#pragma unroll
      for (int b = 0; b < 8; ++b) {
        const float* pp = &phL[b * HH + kloc];
        f32x4 p0 = *(const f32x4*)pp;
        f32x4 p1 = *(const f32x4*)(pp + 4);
        acc[b] = fmaf(p0[0], wf[0], acc[b]);
        acc[b] = fmaf(p0[1], wf[1], acc[b]);
        acc[b] = fmaf(p0[2], wf[2], acc[b]);
        acc[b] = fmaf(p0[3], wf[3], acc[b]);
        acc[b] = fmaf(p1[0], wf[4], acc[b]);
        acc[b] = fmaf(p1[1], wf[5], acc[b]);
        acc[b] = fmaf(p1[2], wf[6], acc[b]);
        acc[b] = fmaf(p1[3], wf[7], acc[b]);
      }
    }
    __syncthreads();  // all done reading phL
    // ---- write partials (overlay phL: 256 threads x 8 f32 = 8KB)
    {
      float* part = phL;
      *(f32x4*)&part[tid * 8] = (f32x4){acc[0], acc[1], acc[2], acc[3]};
      *(f32x4*)&part[tid * 8 + 4] = (f32x4){acc[4], acc[5], acc[6], acc[7]};
    }
    __syncthreads();
    // ---- reduce over 8 k-segments + LSTM cell (threads 0..63: (b, hid))
    if (tid < 64) {
      const float* part = phL;
      float gsum[4];
#pragma unroll
      for (int gt = 0; gt < 4; ++gt) {
        int lc2 = gt * 8 + h_;
        float sm = xg4[gt];
#pragma unroll
        for (int q = 0; q < 8; ++q) sm += part[(q * 32 + lc2) * 8 + b_];
        gsum[gt] = sm;
      }
      int hidx = s * 8 + h_;
      float pc = __hip_atomic_load(&Cs[(size_t)slot * (BB * HH) + b_ * HH + hidx],
                                   __ATOMIC_RELAXED, __HIP_MEMORY_SCOPE_AGENT);
      float c = sigm(gsum[1]) * pc + sigm(gsum[0]) * tanhf(gsum[3]);
      float h = sigm(gsum[2]) * tanhf(c);
      size_t oi = (size_t)(node + 1) * (BB * HH) + b_ * HH + hidx;
      // relaxed agent dword stores: write-through, no L2 dirty (r5 form)
      __hip_atomic_store(&Cs[oi], c, __ATOMIC_RELAXED, __HIP_MEMORY_SCOPE_AGENT);
      __hip_atomic_store(&Hs[oi], h, __ATOMIC_RELAXED, __HIP_MEMORY_SCOPE_AGENT);
      hs_bf[((size_t)b_ * NN + node) * HH + hidx] = f2bf(h);  // normal store
    }
    // publish: wave 0 made all the data stores; drain them, then bump count.
    if (tid == 0) {
      asm volatile("s_waitcnt vmcnt(0)" ::: "memory");
      __hip_atomic_fetch_add(&count[(size_t)node * CSTRIDE], 1, __ATOMIC_RELAXED,
                             __HIP_MEMORY_SCOPE_AGENT);
    }
    __syncthreads();
  }
}

// ---------------- logits = hs_bf (2048x512) @ WoT^T (32000x512) + bo, f32 out
__global__ __launch_bounds__(256) void gemm_kernel(
    const unsigned short* __restrict__ A, const unsigned short* __restrict__ Bt,
    const float* __restrict__ bo, float* __restrict__ C) {
  int bid = blockIdx.x;                    // 0..3999
  int swz = (bid & 7) * 500 + (bid >> 3);  // XCD-contiguous chunks
  int nt = swz >> 4;                       // 0..249
  int mt = swz & 15;                       // 0..15
  int tid = threadIdx.x;
  int wave = tid >> 6;
  int lane = tid & 63;
  int wr = wave >> 1, wc = wave & 1;
  int lr = lane & 15, lh = lane >> 4;
  __shared__ __align__(16) unsigned short Al[128 * 32];
  __shared__ __align__(16) unsigned short Bl[128 * 32];
  int m0 = mt * 128, n0 = nt * 128;
  f32x4 acc[4][4];
#pragma unroll
  for (int i = 0; i < 4; ++i)
#pragma unroll
    for (int j = 0; j < 4; ++j) acc[i][j] = (f32x4){0.f, 0.f, 0.f, 0.f};

  for (int k0 = 0; k0 < HH; k0 += 32) {
#pragma unroll
    for (int q = 0; q < 2; ++q) {
      int off = wave * 2048 + q * 1024 + lane * 16;
      int r = off >> 6;
      int cb = off & 63;
      const unsigned short* ga = A + (size_t)(m0 + r) * HH + k0 + (cb >> 1);
      const unsigned short* gb = Bt + (size_t)(n0 + r) * HH + k0 + (cb >> 1);
      __builtin_amdgcn_global_load_lds(
          (const __attribute__((address_space(1))) unsigned int*)ga,
          (__attribute__((address_space(3))) unsigned int*)((char*)Al + wave * 2048 + q * 1024),
          16, 0, 0);
      __builtin_amdgcn_global_load_lds(
          (const __attribute__((address_space(1))) unsigned int*)gb,
          (__attribute__((address_space(3))) unsigned int*)((char*)Bl + wave * 2048 + q * 1024),
          16, 0, 0);
    }
    __syncthreads();
    bf16x8 af[4], bfr[4];
#pragma unroll
    for (int i = 0; i < 4; ++i) {
      af[i] = *(const bf16x8*)&Al[(wr * 64 + i * 16 + lr) * 32 + lh * 8];
      bfr[i] = *(const bf16x8*)&Bl[(wc * 64 + i * 16 + lr) * 32 + lh * 8];
    }
#pragma unroll
    for (int i = 0; i < 4; ++i)
#pragma unroll
      for (int j = 0; j < 4; ++j)
        acc[i][j] = __builtin_amdgcn_mfma_f32_16x16x32_bf16(af[i], bfr[j], acc[i][j], 0, 0, 0);
    __syncthreads();
  }
#pragma unroll
  for (int j = 0; j < 4; ++j) {
    int v = n0 + wc * 64 + j * 16 + lr;
    float bias = bo[v];
#pragma unroll
    for (int i = 0; i < 4; ++i) {
#pragma unroll
      for (int r2 = 0; r2 < 4; ++r2) {
        int m = m0 + wr * 64 + i * 16 + lh * 4 + r2;
        C[(size_t)m * VV + v] = acc[i][j][r2] + bias;
      }
    }
  }
}

// ---------------- workspace layout (bytes)
static const size_t OFF_COUNT = 0;                       // 256*64 = 16384 (padded)
static const size_t OFF_ABORT = 16384;                   // 64B sector
static const size_t OFF_ORDER = 16448;                   // int[256] (region ends 17472)
static const size_t OFF_HS = 20480;                      // 257*8*512*4 = 4210688
static const size_t OFF_CS = OFF_HS + 4210688;           // 4231168
static const size_t OFF_XG = OFF_CS + 4210688;           // 8441856, 16777216 B
static const size_t OFF_HSBF = OFF_XG + 16777216;        // 25219072, 2097152 B
static const size_t OFF_WOT = OFF_HSBF + 2097152;        // 27316224, 32768000 B
// total = 60,084,224 bytes

extern "C" void kernel_launch(void* const* d_in, const int* in_sizes, int n_in,
                              void* d_out, int out_size, void* d_ws, size_t ws_size,
                              hipStream_t stream) {
  const int* rel_ids = (const int*)d_in[0];
  const int* sent_ids = (const int*)d_in[1];
  const int* parent = (const int*)d_in[2];
  const float* root_h = (const float*)d_in[3];
  const float* word_emb = (const float*)d_in[4];
  const float* rel_emb = (const float*)d_in[5];
  const float* Wx = (const float*)d_in[6];
  const float* Wh = (const float*)d_in[7];
  const float* bias = (const float*)d_in[8];
  const float* Wo = (const float*)d_in[9];
  const float* bo = (const float*)d_in[10];
  float* out = (float*)d_out;

  char* ws = (char*)d_ws;
  int* count = (int*)(ws + OFF_COUNT);
  int* abortf = (int*)(ws + OFF_ABORT);
  int* order = (int*)(ws + OFF_ORDER);
  float* Hs = (float*)(ws + OFF_HS);
  float* Cs = (float*)(ws + OFF_CS);
  float* Xg = (float*)(ws + OFF_XG);
  unsigned short* hs_bf = (unsigned short*)(ws + OFF_HSBF);
  unsigned short* WoT = (unsigned short*)(ws + OFF_WOT);

  hipMemsetAsync(ws, 0, 20480, stream);  // counters + abort + order region
  init_kernel<<<16, 256, 0, stream>>>(root_h, Hs, Cs);
  levels_kernel<<<1, 64, 0, stream>>>(parent, order);
  xg_kernel<<<dim3(8, 256), 256, 0, stream>>>(rel_ids, sent_ids, parent, word_emb,
                                              rel_emb, Wx, bias, Xg);
  wot_kernel<<<dim3(500, 8), 256, 0, stream>>>(Wo, WoT);
  {
    int ng = 12;  // 64 slices x 12 groups = 768 blocks (3 blocks/CU @ 48KB LDS)
    void* args[] = {(void*)&parent, (void*)&Wh, (void*)&Xg, (void*)&Hs,
                    (void*)&Cs, (void*)&hs_bf, (void*)&order, (void*)&count,
                    (void*)&abortf, (void*)&ng};
    hipError_t e = hipLaunchCooperativeKernel((void*)scan_kernel, dim3(64 * 12),
                                              dim3(256), args, 0, stream);
    if (e != hipSuccess) {
      ng = 8;  // 512 blocks (2 blocks/CU)
      e = hipLaunchCooperativeKernel((void*)scan_kernel, dim3(64 * 8), dim3(256),
                                     args, 0, stream);
      if (e != hipSuccess) {
        // last resort: plain launch (watchdog-bounded, 512 blocks fit)
        scan_kernel<<<512, 256, 0, stream>>>(parent, Wh, Xg, Hs, Cs, hs_bf,
                                             order, count, abortf, 8);
      }
    }
  }
  gemm_kernel<<<4000, 256, 0, stream>>>(hs_bf, WoT, bo, out);
}